// Round 3
// baseline (386.948 us; speedup 1.0000x reference)
//
#include <hip/hip_runtime.h>
#include <math.h>

#define N_    8
#define CIN   32
#define COUT  32
#define AUX   128
#define HID   256
#define HWD   384
#define HW2   (HWD*HWD)
#define MODOUT (COUT*CIN*9)   // 9216

typedef short s8v  __attribute__((ext_vector_type(8)));   // 8 bf16 (4 VGPRs)
typedef short s4v  __attribute__((ext_vector_type(4)));   // 4 bf16 (2 VGPRs)
typedef float f16v __attribute__((ext_vector_type(16)));  // 32x32 C/D frag

__device__ __forceinline__ unsigned short f2b(float f) {  // fp32 -> bf16 RNE
    unsigned u = __float_as_uint(f);
    u += 0x7FFF + ((u >> 16) & 1);
    return (unsigned short)(u >> 16);
}
__device__ __forceinline__ float prelu_f(float z, float a) { return z >= 0.f ? z : a * z; }

// ---------- Kernel 1: h (redundant per block) + mod weights + bias ---------
// 288 blocks x 256. Each block computes h for all 8 samples (fc_w1 L2-hot),
// then its 32 columns of the second GEMM with K split across 8 thread groups.
// Blocks 0..7 additionally compute the learned bias for sample blockIdx.x.
__global__ __launch_bounds__(256) void mod_all(
    const float* __restrict__ y,
    const float* __restrict__ fc_w1, const float* __restrict__ fc_b1, const float* __restrict__ fc_a,
    const float* __restrict__ fc_w2, const float* __restrict__ fc_b2,
    const float* __restrict__ weight,
    const float* __restrict__ b_w1,  const float* __restrict__ b_b1,  const float* __restrict__ b_a,
    const float* __restrict__ b_w2,  const float* __restrict__ b_b2,
    unsigned short* __restrict__ wmod, float* __restrict__ ws_bias)
{
    __shared__ float ly[N_*AUX];        // 4 KB
    __shared__ float lh[N_*HID];        // 8 KB
    __shared__ float red[8][32][N_];    // 8 KB
    const int tid = threadIdx.x;
    for (int i = tid; i < N_*AUX; i += 256) ly[i] = y[i];
    __syncthreads();
    {   // h[n][j] for all samples, thread j = tid
        const int j = tid;
        const float b1 = fc_b1[j];
        float hacc[N_];
#pragma unroll
        for (int n = 0; n < N_; ++n) hacc[n] = b1;
        for (int k = 0; k < AUX; ++k) {
            const float w = fc_w1[k*HID + j];
#pragma unroll
            for (int n = 0; n < N_; ++n) hacc[n] += ly[n*AUX + k] * w;
        }
        const float a1 = fc_a[0];
#pragma unroll
        for (int n = 0; n < N_; ++n) lh[n*HID + j] = prelu_f(hacc[n], a1);
    }
    __syncthreads();
    const int ml = tid & 31, jc = tid >> 5;
    const int m  = blockIdx.x * 32 + ml;
    {
        float acc[N_];
#pragma unroll
        for (int n = 0; n < N_; ++n) acc[n] = 0.f;
        for (int jj = 0; jj < 32; ++jj) {
            const int j = jc*32 + jj;
            const float w = fc_w2[j*MODOUT + m];
#pragma unroll
            for (int n = 0; n < N_; ++n) acc[n] += lh[n*HID + j] * w;
        }
#pragma unroll
        for (int n = 0; n < N_; ++n) red[jc][ml][n] = acc[n];
    }
    __syncthreads();
    {
        const int nn = jc;              // thread = (column ml, sample nn)
        float s = fc_b2[m];
#pragma unroll
        for (int k = 0; k < 8; ++k) s += red[k][ml][nn];
        const float mod = 1.f / (1.f + __expf(-s));
        const float v = mod * weight[m];
        const int co = m / 288, r = m - co*288;
        const int ci = r / 9,  tap = r - ci*9;
        wmod[((nn*9 + tap)*COUT + co)*CIN + ci] = f2b(v);
    }
    if (blockIdx.x < N_) {              // bias path, block-uniform branch
        const int n = blockIdx.x;
        const int j = tid;
        float hb = b_b1[j];
        for (int k = 0; k < AUX; ++k) hb += ly[n*AUX + k] * b_w1[k*HID + j];
        __syncthreads();                // red no longer read
        float* sc = &red[0][0][0];
        sc[j] = prelu_f(hb, b_a[0]);
        __syncthreads();
        if (j < COUT) {
            float s = b_b2[j];
            for (int k = 0; k < HID; ++k) s += sc[k] * b_w2[k*COUT + j];
            ws_bias[n*COUT + j] = s;
        }
    }
}

// ---------------- Kernel 2: conv as 9 shifted 1x1 GEMMs via MFMA -----------
// Tile 8 rows x 64 cols x 32 cout. K=32 staged once (single barrier).
// Each wave processes its 4 C-frags SEQUENTIALLY (16 AGPR live).
// LDS col stride padded 32->36 shorts: B-read lane stride = 18 dwords,
// gcd(18,32)=2 -> 2 lanes/bank -> conflict-free ds_read_b64 pairs.
#define TH   8
#define TCOL 64
#define CS   36             // shorts per (row,col) cell: 32 ci + 4 pad
#define LC   72             // staged cols (TCOL + 8 halo)
#define RS   (LC*CS)        // 2592 shorts per staged row

__global__ __launch_bounds__(256, 3) void conv_mfma(
    const float* __restrict__ x,
    const unsigned short* __restrict__ wmod,
    const float* __restrict__ bias,
    float* __restrict__ out)
{
    __shared__ short lx[10*RS];         // 51840 B

    const int tid = threadIdx.x;
    const int n   = blockIdx.z;
    const int gh  = blockIdx.y * TH;
    const int gw  = blockIdx.x * TCOL;
    const int lane = tid & 63;
    const int wv  = tid >> 6;           // wave 0..3
    const int lm  = lane & 31;          // co (A) / pixel (B,D)
    const int h   = lane >> 5;          // k-oct selector

    // A-frags for both K-halves: 18 x 16B loads, overlap with staging
    s8v a[2][9];
#pragma unroll
    for (int cc = 0; cc < 2; ++cc)
#pragma unroll
        for (int t = 0; t < 9; ++t)
            a[cc][t] = *(const s8v*)&wmod[(((n*9 + t)*COUT + lm)*CIN) + cc*16 + h*8];

    float br[16];
#pragma unroll
    for (int r = 0; r < 16; ++r) {
        const int co = (r & 3) + 8*(r >> 2) + 4*h;
        br[r] = bias[n*COUT + co];
    }

    // ---- stage all 32 channels, 10 rows x 72 cols, bf16, padded cells ----
    for (int it = tid; it < 720; it += 256) {
        const int o   = it & 3;          // ci oct (8 channels)
        const int rc  = it >> 2;
        const int row = rc / 18;
        const int q   = rc - row*18;     // col quad
        const int gr  = gh + row - 1;
        const int gc  = gw + q*4 - 4;
        float va[8][4];
        if ((unsigned)gr < HWD && (unsigned)gc < HWD) {
            const float* xb = x + ((size_t)(n*CIN + o*8)*HWD + gr)*HWD + gc;
#pragma unroll
            for (int ci = 0; ci < 8; ++ci) {
                const float4 t = *(const float4*)(xb + (size_t)ci*HW2);
                va[ci][0] = t.x; va[ci][1] = t.y; va[ci][2] = t.z; va[ci][3] = t.w;
            }
        } else {
#pragma unroll
            for (int ci = 0; ci < 8; ++ci)
                va[ci][0] = va[ci][1] = va[ci][2] = va[ci][3] = 0.f;
        }
#pragma unroll
        for (int c = 0; c < 4; ++c) {
            const unsigned w0 = (unsigned)f2b(va[0][c]) | ((unsigned)f2b(va[1][c]) << 16);
            const unsigned w1 = (unsigned)f2b(va[2][c]) | ((unsigned)f2b(va[3][c]) << 16);
            const unsigned w2 = (unsigned)f2b(va[4][c]) | ((unsigned)f2b(va[5][c]) << 16);
            const unsigned w3 = (unsigned)f2b(va[6][c]) | ((unsigned)f2b(va[7][c]) << 16);
            const int idx = row*RS + (q*4 + c)*CS + o*8;   // short index, 8B aligned
            *(int2*)&lx[idx]     = make_int2((int)w0, (int)w1);
            *(int2*)&lx[idx + 4] = make_int2((int)w2, (int)w3);
        }
    }
    __syncthreads();                     // the ONLY barrier

    // ---- 4 frags per wave, sequential (one 16-AGPR acc live) ----
#pragma unroll
    for (int g = 0; g < 4; ++g) {
        const int rr = 2*wv + (g & 1);
        const int cg = g >> 1;
        f16v acc;
#pragma unroll
        for (int r = 0; r < 16; ++r) acc[r] = 0.f;
#pragma unroll
        for (int cc = 0; cc < 2; ++cc) {
            const int q8 = (cc*2 + h) * 8;   // k-group short offset in cell
#pragma unroll
            for (int kh = 0; kh < 3; ++kh) {
                const int rowb = (rr + kh)*RS + q8;
#pragma unroll
                for (int kw = 0; kw < 3; ++kw) {
                    const int off = rowb + (cg*32 + lm + 3 + kw)*CS;
                    union { s8v v; s4v hf[2]; } ub;
                    ub.hf[0] = *(const s4v*)&lx[off];
                    ub.hf[1] = *(const s4v*)&lx[off + 4];
                    acc = __builtin_amdgcn_mfma_f32_32x32x16_bf16(a[cc][kh*3 + kw], ub.v, acc, 0, 0, 0);
                }
            }
        }
        float* ob = out + (size_t)(n*COUT)*HW2 + (size_t)(gh + rr)*HWD + gw + cg*32 + lm;
#pragma unroll
        for (int r = 0; r < 16; ++r) {
            const int co = (r & 3) + 8*(r >> 2) + 4*h;
            ob[(size_t)co*HW2] = acc[r] + br[r];
        }
    }
}

extern "C" void kernel_launch(void* const* d_in, const int* in_sizes, int n_in,
                              void* d_out, int out_size, void* d_ws, size_t ws_size,
                              hipStream_t stream) {
    const float* x     = (const float*)d_in[0];
    const float* y     = (const float*)d_in[1];
    const float* weight= (const float*)d_in[2];
    const float* fc_w1 = (const float*)d_in[3];
    const float* fc_b1 = (const float*)d_in[4];
    const float* fc_a  = (const float*)d_in[5];
    const float* fc_w2 = (const float*)d_in[6];
    const float* fc_b2 = (const float*)d_in[7];
    const float* b_w1  = (const float*)d_in[8];
    const float* b_b1  = (const float*)d_in[9];
    const float* b_a   = (const float*)d_in[10];
    const float* b_w2  = (const float*)d_in[11];
    const float* b_b2  = (const float*)d_in[12];
    float* out = (float*)d_out;

    unsigned short* ws_wmod = (unsigned short*)d_ws;                 // 147456 B
    float* ws_bias = (float*)((char*)d_ws + (size_t)MODOUT*N_*2);    // 256 f

    mod_all<<<MODOUT/32, 256, 0, stream>>>(y, fc_w1, fc_b1, fc_a, fc_w2, fc_b2,
                                           weight, b_w1, b_b1, b_a, b_w2, b_b2,
                                           ws_wmod, ws_bias);
    conv_mfma<<<dim3(HWD/TCOL, HWD/TH, N_), 256, 0, stream>>>(x, ws_wmod, ws_bias, out);
}